// Round 7
// baseline (413.691 us; speedup 1.0000x reference)
//
#include <hip/hip_runtime.h>
#include <stdint.h>

// Problem constants: x [B=2, S=4096, K=4096] -> M = 8192; weight [N=4096, K=4096]
#define M_DIM 8192
#define N_DIM 4096
#define K_DIM 4096

using int4v = __attribute__((ext_vector_type(4))) int;

// ---------------------------------------------------------------------------
// Pack kernel: int32 (widened int8 in [-127,127]) -> int8 bytes.
// One int4 (16 B) read per thread -> 4 B write, fully coalesced.
// ---------------------------------------------------------------------------
__global__ __launch_bounds__(256) void pack_kernel(const int4* __restrict__ sx,
                                                   const int4* __restrict__ sw,
                                                   unsigned int* __restrict__ dst,
                                                   int nx, int ntot) {
    int idx = blockIdx.x * blockDim.x + threadIdx.x;
    if (idx >= ntot) return;
    int4 v = (idx < nx) ? sx[idx] : sw[idx - nx];
    dst[idx] = (v.x & 0xff) | ((v.y & 0xff) << 8) | ((v.z & 0xff) << 16) |
               ((v.w & 0xff) << 24);
}

// ---------------------------------------------------------------------------
// i8 GEMM, 128x128 block tile, 256 threads = 4 waves in 2x2, each wave a
// 64x64 tile of 4x4 16x16 MFMAs (mfma_i32_16x16x64_i8, BK=64).
//
// STAGING RESTRUCTURE (r7): buffer_load -> VGPR -> ds_write instead of
// global_load_lds. Why: __syncthreads must drain vmcnt(0) when
// global_load_lds is outstanding (it writes LDS), serializing the full
// staging latency into every K-iter -- the r2-r6 177-181 us invariant.
// With register staging, the barrier needs only lgkmcnt(0); the global
// loads are waited fine-grained (vmcnt(N)) where ds_write consumes them,
// and the 2-deep pipeline (load k+2 / write k+1 / compute k) makes them
// a full iteration old by then. Latency off the critical path.
//
// LDS bank swizzle (r5, measured conflicts -> 0): 16-B chunk (row, gs)
// stores global col-group gs ^ ((row>>1)&3); read side XOR-corrects.
// ds_write is per-lane addressed, so the same layout carries over.
//
// C[m,n] = sum_k x[m,k] * w[n,k]  (both operands K-major).
// A/B frag: m=lane&15, k-group=lane>>4.  C/D: col=lane&15, row=(lane>>4)*4+reg.
// ---------------------------------------------------------------------------
__global__ __launch_bounds__(256, 2) void gemm_i8_kernel(
    const char* __restrict__ Aq,   // [M, K] int8
    const char* __restrict__ Bq,   // [N, K] int8
    const int* __restrict__ bias,  // [N] int32 (widened int8)
    const float* __restrict__ a_ptr,
    const float* __restrict__ b_ptr,
    int32_t* __restrict__ out)     // [M, N] int32 holding int8 values
{
    __shared__ char As[2][128 * 64];   // 2 x 8 KiB
    __shared__ char Bs[2][128 * 64];   // 2 x 8 KiB

    const int tid  = threadIdx.x;
    const int lane = tid & 63;
    const int wave = tid >> 6;
    const int wr   = wave >> 1;   // wave row (0..1) -> 64-row slab
    const int wc   = wave & 1;    // wave col (0..1) -> 64-col slab
    const int m0   = blockIdx.y * 128;
    const int n0   = blockIdx.x * 128;

    const float alpha = *a_ptr;
    const float beta  = *b_ptr;

    int4v acc[4][4] = {};  // 64 accumulator regs

    // Staging: thread t owns LDS chunk t (row = t>>2), swizzled col-group.
    const int srow = tid >> 2;                        // 0..63
    const int scol = ((tid & 3) ^ ((srow >> 1) & 3)) * 16;

    const char* aG0 = Aq + (size_t)(m0 + srow) * K_DIM + scol;
    const char* aG1 = aG0 + (size_t)64 * K_DIM;
    const char* bG0 = Bq + (size_t)(n0 + srow) * K_DIM + scol;
    const char* bG1 = bG0 + (size_t)64 * K_DIM;
    const int l0 = tid * 16;
    const int l1 = tid * 16 + 4096;

    // Fragment read coords: lane holds A[m=lane&15][k-group=lane>>4], with
    // the swizzle XOR folded into the byte offset (key = (fr>>1)&3).
    const int fr  = lane & 15;
    const int gw  = lane >> 4;
    const int fko = (gw ^ ((fr >> 1) & 3)) * 16;

    // --- Prologue: tile 0 -> regs -> LDS[0]; tile 1 -> regs. ---
    int4v ra0 = *(const int4v*)aG0;
    int4v ra1 = *(const int4v*)aG1;
    int4v rb0 = *(const int4v*)bG0;
    int4v rb1 = *(const int4v*)bG1;
    *(int4v*)&As[0][l0] = ra0;
    *(int4v*)&As[0][l1] = ra1;
    *(int4v*)&Bs[0][l0] = rb0;
    *(int4v*)&Bs[0][l1] = rb1;
    ra0 = *(const int4v*)(aG0 + 64);
    ra1 = *(const int4v*)(aG1 + 64);
    rb0 = *(const int4v*)(bG0 + 64);
    rb1 = *(const int4v*)(bG1 + 64);
    __syncthreads();  // lgkmcnt(0): tile-0 ds_writes visible

#pragma unroll 2
    for (int k0 = 0; k0 < K_DIM; k0 += 64) {
        const int cur = (k0 >> 6) & 1;
        const int nxt = cur ^ 1;

        // Stage tile k+1 (regs, loaded last iter -> vmcnt wait is ~1 iter
        // old, free) into the buffer the previous iter finished reading.
        if (k0 + 64 < K_DIM) {
            *(int4v*)&As[nxt][l0] = ra0;
            *(int4v*)&As[nxt][l1] = ra1;
            *(int4v*)&Bs[nxt][l0] = rb0;
            *(int4v*)&Bs[nxt][l1] = rb1;
        }
        // Issue global loads for tile k+2 (consumed next iter).
        if (k0 + 128 < K_DIM) {
            ra0 = *(const int4v*)(aG0 + k0 + 128);
            ra1 = *(const int4v*)(aG1 + k0 + 128);
            rb0 = *(const int4v*)(bG0 + k0 + 128);
            rb1 = *(const int4v*)(bG1 + k0 + 128);
        }

        int4v af[4], bf[4];
#pragma unroll
        for (int i = 0; i < 4; ++i)
            af[i] = *(const int4v*)&As[cur][(wr * 64 + i * 16 + fr) * 64 + fko];
#pragma unroll
        for (int j = 0; j < 4; ++j)
            bf[j] = *(const int4v*)&Bs[cur][(wc * 64 + j * 16 + fr) * 64 + fko];

#pragma unroll
        for (int i = 0; i < 4; ++i)
#pragma unroll
            for (int j = 0; j < 4; ++j)
                acc[i][j] = __builtin_amdgcn_mfma_i32_16x16x64_i8(
                    af[i], bf[j], acc[i][j], 0, 0, 0);

        // lgkmcnt(0)-only barrier: orders this iter's ds_writes/reads;
        // no vmcnt drain needed (pending vmem are register loads).
        __syncthreads();
    }

    // Epilogue: C/D layout col = lane&15, row = (lane>>4)*4 + reg.
    const int orow = (lane >> 4) * 4;
    const int ocol = lane & 15;
#pragma unroll
    for (int j = 0; j < 4; ++j) {
        const int gn = n0 + wc * 64 + j * 16 + ocol;
        const float bb = beta * (float)bias[gn];
#pragma unroll
        for (int i = 0; i < 4; ++i) {
            const int gm = m0 + wr * 64 + i * 16 + orow;
#pragma unroll
            for (int r = 0; r < 4; ++r) {
                float v = alpha * (float)acc[i][j][r] + bb;
                v = rintf(v);                       // round half-to-even (numpy)
                v = fminf(fmaxf(v, -128.0f), 127.0f);
                out[(size_t)(gm + r) * N_DIM + gn] = (int32_t)v;
            }
        }
    }
}

// ---------------------------------------------------------------------------
extern "C" void kernel_launch(void* const* d_in, const int* in_sizes, int n_in,
                              void* d_out, int out_size, void* d_ws, size_t ws_size,
                              hipStream_t stream) {
    const int*   x    = (const int*)d_in[0];    // [M, K] widened int8
    const int*   w    = (const int*)d_in[1];    // [N, K] widened int8
    const int*   bias = (const int*)d_in[2];    // [N]
    const float* a    = (const float*)d_in[3];  // alpha scalar
    const float* b    = (const float*)d_in[4];  // beta scalar
    int32_t*     out  = (int32_t*)d_out;        // [M, N]

    char* xq = (char*)d_ws;                     // 32 MiB packed x
    const int nx   = (M_DIM * K_DIM) / 4;       // int4-groups in x
    const int nw   = (N_DIM * K_DIM) / 4;
    const int ntot = nx + nw;
    pack_kernel<<<(ntot + 255) / 256, 256, 0, stream>>>(
        (const int4*)x, (const int4*)w, (unsigned int*)xq, nx, ntot);

    char* wq = xq + (size_t)M_DIM * K_DIM;      // 16 MiB packed weight

    dim3 grid(N_DIM / 128, M_DIM / 128);        // 32 x 64 = 2048 blocks
    gemm_i8_kernel<<<grid, 256, 0, stream>>>(xq, wq, bias, a, b, out);
}